// Round 9
// baseline (146.472 us; speedup 1.0000x reference)
//
#include <hip/hip_runtime.h>
#include <stdint.h>

// ---------------- problem constants ----------------
constexpr int Wd  = 640;
constexpr int Hd  = 480;
constexpr int Bd  = 8;
constexpr int Gd  = 368640;          // int(B*H*W*0.15)
constexpr int HWd = Hd * Wd;         // 307200
constexpr int GRIDP = HWd / 256;     // 1200
constexpr int GRIDC = Gd / 256;      // 1440  (1 thread/group: max gather ILP)
constexpr int NBIN  = 4096;          // top-12-bit count histogram
constexpr int NREP  = 4;             // global hist replicas (cut hot-bin contention)

// ---------------- workspace layout (bytes) ----------------
#define WS_SUM_ALL  0                        // double: exact sum of masked L
#define WS_DONE1    32                       // u32: completion counter
#define HISTC_OFF   64                       // NREP x NBIN u32 (count per bin)
#define CTRL_BYTES  (HISTC_OFF + NREP*NBIN*4)
#define CTRL_WORDS  (CTRL_BYTES / 4)
#define PACK_OFF    ((CTRL_BYTES + 255) & ~255)   // float pk[HWd][16], 64B/pixel

// ---------------- kernel 0: repack depth (pixel-major, batch-minor) + zero ctrl ----------------
__global__ __launch_bounds__(256) void k_pack(const float* __restrict__ gt,
                                              const float* __restrict__ pd,
                                              unsigned char* __restrict__ ws)
{
    const int o = blockIdx.x * 256 + threadIdx.x;
    float v[16];
#pragma unroll
    for (int b = 0; b < Bd; ++b) {
        v[2 * b]     = gt[b * HWd + o];
        v[2 * b + 1] = pd[b * HWd + o];
    }
    float4* __restrict__ dst = (float4*)(ws + PACK_OFF) + (size_t)o * 4;
#pragma unroll
    for (int c = 0; c < 4; ++c)
        dst[c] = make_float4(v[4 * c], v[4 * c + 1], v[4 * c + 2], v[4 * c + 3]);

    if (blockIdx.x == 0) {
        unsigned* __restrict__ ctrl = (unsigned*)ws;
        for (int k = threadIdx.x; k < CTRL_WORDS; k += 256) ctrl[k] = 0u;
    }
}

// ---------------- kernel 1: single-pass L + mask + count-hist + fused select ----------------
// LESSONS BAKED IN:
//  - 1 thread/group, 12 upfront float4 gathers, NO vgpr cap (R3/R7: split layout
//    -> VGPR 32 -> serialized gathers, +40us).
//  - NO __threadfence (R4: agent fence = per-XCD L2 writeback+invalidate, +65us).
//  - COUNT-ONLY histogram: per-bin f64 sum merge had hot-bin global-atomic
//    serialization (R6/R8: +6..10us). Dropped mass uses bin midpoints:
//    worst-case err (dropped/denom)*2^-4 ~ 6e-3 << 4.16e-2 threshold.
//  - 4x replicated global hist (blockIdx&3) cuts hot-bin contention.
// n = exact hist total; sum_all = exact (1 double atomic per block).
__global__ __launch_bounds__(256) void k_compute(
    const int* __restrict__ p1x, const int* __restrict__ p1y,
    const int* __restrict__ p2x, const int* __restrict__ p2y,
    const int* __restrict__ p3x, const int* __restrict__ p3y,
    unsigned char* __restrict__ ws, float* __restrict__ out)
{
    __shared__ unsigned lhc[NBIN];
    __shared__ double   ps[256];
    __shared__ double   wsum[4];
    __shared__ int      lastflag;
    const int t = threadIdx.x;
    for (int k = t; k < NBIN; k += 256) lhc[k] = 0u;
    __syncthreads();

    const int g = blockIdx.x * 256 + t;
    const int x1 = p1x[g], y1 = p1y[g];
    const int x2 = p2x[g], y2 = p2y[g];
    const int x3 = p3x[g], y3 = p3y[g];
    const int o1 = y1 * Wd + x1, o2 = y2 * Wd + x2, o3 = y3 * Wd + x3;
    const float u1 = (float)x1 - 320.0f, v1 = (float)y1 - 240.0f;
    const float u2 = (float)x2 - 320.0f, v2 = (float)y2 - 240.0f;
    const float u3 = (float)x3 - 320.0f, v3 = (float)y3 - 240.0f;
    constexpr float RF = 1.0f / 519.0f;

    // 3 random 64B lines, issued as 12 independent float4 loads (max MLP)
    const float4* __restrict__ pk4 = (const float4*)(ws + PACK_OFF);
    float4 A[4], Bv[4], Cv[4];
#pragma unroll
    for (int c = 0; c < 4; ++c) {
        A[c]  = pk4[(size_t)o1 * 4 + c];
        Bv[c] = pk4[(size_t)o2 * 4 + c];
        Cv[c] = pk4[(size_t)o3 * 4 + c];
    }
    const float* __restrict__ P1 = (const float*)A;
    const float* __restrict__ P2 = (const float*)Bv;
    const float* __restrict__ P3 = (const float*)Cv;

    double lsum = 0.0;

#pragma unroll
    for (int b = 0; b < Bd; ++b) {
        const float d1 = P1[2 * b], e1 = P1[2 * b + 1];
        const float d2 = P2[2 * b], e2 = P2[2 * b + 1];
        const float d3 = P3[2 * b], e3 = P3[2 * b + 1];

        const float a1 = fabsf(d1) * RF, a2 = fabsf(d2) * RF, a3 = fabsf(d3) * RF;
        const float gx1 = u1 * a1, gy1 = v1 * a1;
        const float gx2 = u2 * a2, gy2 = v2 * a2;
        const float gx3 = u3 * a3, gy3 = v3 * a3;

        const float D0x = gx2 - gx1, D0y = gy2 - gy1, D0z = d2 - d1;
        const float D1x = gx3 - gx1, D1y = gy3 - gy1, D1z = d3 - d1;
        const float D2x = gx3 - gx2, D2y = gy3 - gy2, D2z = d3 - d2;

        const float e00 = D0x*D0x + D0y*D0y + D0z*D0z;
        const float e11 = D1x*D1x + D1y*D1y + D1z*D1z;
        const float e22 = D2x*D2x + D2y*D2y + D2z*D2z;
        const float e01 = D0x*D1x + D0y*D1y + D0z*D1z;
        const float e02 = D0x*D2x + D0y*D2y + D0z*D2z;
        const float e12 = D1x*D2x + D1y*D2y + D1z*D2z;
        const float n0 = sqrtf(e00), n1 = sqrtf(e11), n2 = sqrtf(e22);
        constexpr float DC = 0.867f;
        int cnt = 0;
        cnt += (fabsf(e00) > DC * (n0*n0 + 1e-8f));
        cnt += (fabsf(e11) > DC * (n1*n1 + 1e-8f));
        cnt += (fabsf(e22) > DC * (n2*n2 + 1e-8f));
        cnt += 2 * (fabsf(e01) > DC * (n0*n1 + 1e-8f));
        cnt += 2 * (fabsf(e02) > DC * (n0*n2 + 1e-8f));
        cnt += 2 * (fabsf(e12) > DC * (n1*n2 + 1e-8f));
        const bool mask_cos = cnt > 3;

        const bool mx = (fabsf(D0x) < 0.01f) | (fabsf(D1x) < 0.01f) | (fabsf(D2x) < 0.01f);
        const bool my = (fabsf(D0y) < 0.01f) | (fabsf(D1y) < 0.01f) | (fabsf(D2y) < 0.01f);
        const bool mz = (fabsf(D0z) < 0.01f) | (fabsf(D1z) < 0.01f) | (fabsf(D2z) < 0.01f);
        const bool mask = !((mx && my && mz) || mask_cos);

        const float b1s = fabsf(e1) * RF, b2s = fabsf(e2) * RF, b3s = fabsf(e3) * RF;
        float qx1 = u1 * b1s, qy1 = v1 * b1s, qz1 = e1;
        float qx2 = u2 * b2s, qy2 = v2 * b2s, qz2 = e2;
        float qx3 = u3 * b3s, qy3 = v3 * b3s, qz3 = e3;
        // reference's zmask broadcast: coordinate ROW c of all points
        const bool zm0 = (qz1 == 0.0f), zm1 = (qz2 == 0.0f), zm2 = (qz3 == 0.0f);
        if (zm0) { qx1 = qx2 = qx3 = 1e-4f; }
        if (zm1) { qy1 = qy2 = qy3 = 1e-4f; }
        if (zm2) { qz1 = qz2 = qz3 = 1e-4f; }

        const float P0x = qx2 - qx1, P0y = qy2 - qy1, P0z = qz2 - qz1;
        const float Q1x = qx3 - qx1, Q1y = qy3 - qy1, Q1z = qz3 - qz1;

        const float gnx = D0y * D1z - D0z * D1y;
        const float gny = D0z * D1x - D0x * D1z;
        const float gnz = D0x * D1y - D0y * D1x;
        const float dnx = P0y * Q1z - P0z * Q1y;
        const float dny = P0z * Q1x - P0x * Q1z;
        const float dnz = P0x * Q1y - P0y * Q1x;

        float gnn = sqrtf(gnx*gnx + gny*gny + gnz*gnz);
        float dnn = sqrtf(dnx*dnx + dny*dny + dnz*dnz);
        if (gnn == 0.0f) gnn = 0.01f;
        if (dnn == 0.0f) dnn = 0.01f;
        const float rg = 1.0f / gnn, rd = 1.0f / dnn;
        const float L = fabsf(gnx*rg - dnx*rd) + fabsf(gny*rg - dny*rd) + fabsf(gnz*rg - dnz*rd);

        if (mask) {
            lsum += (double)L;
            atomicAdd(&lhc[__float_as_uint(L) >> 20], 1u);
        }
    }

    // exact sum_all: wave shuffle then one double atomic per block
#pragma unroll
    for (int off = 32; off > 0; off >>= 1) lsum += __shfl_down(lsum, off);
    if ((t & 63) == 0) wsum[t >> 6] = lsum;
    __syncthreads();
    if (t == 0)
        atomicAdd((double*)(ws + WS_SUM_ALL), wsum[0] + wsum[1] + wsum[2] + wsum[3]);

    // merge count hist into this block's replica
    unsigned* __restrict__ gc = (unsigned*)(ws + HISTC_OFF) + (blockIdx.x & (NREP - 1)) * NBIN;
    for (int k = t; k < NBIN; k += 256) {
        const unsigned c = lhc[k];
        if (c) atomicAdd(&gc[k], c);
    }

    // ---- fence-free completion: __syncthreads() drains vmcnt for every wave ----
    __syncthreads();
    if (t == 0) {
        const unsigned prev = __hip_atomic_fetch_add((unsigned*)(ws + WS_DONE1), 1u,
                                                     __ATOMIC_RELAXED, __HIP_MEMORY_SCOPE_AGENT);
        lastflag = (prev == (unsigned)(gridDim.x - 1));
    }
    __syncthreads();
    if (!lastflag) return;

    // ---- last block: scan counts -> n, cutoff bin; midpoint-approx dropped sum ----
    const unsigned* __restrict__ gcb = (const unsigned*)(ws + HISTC_OFF);
    unsigned lc[16]; double lwv[16];
    unsigned cs = 0; double wsd = 0.0;
#pragma unroll
    for (int k = 0; k < 16; ++k) {
        const int bin = t * 16 + k;
        unsigned c = 0;
#pragma unroll
        for (int r = 0; r < NREP; ++r)
            c += __hip_atomic_load(&gcb[r * NBIN + bin],
                                   __ATOMIC_RELAXED, __HIP_MEMORY_SCOPE_AGENT);
        lc[k] = c;
        const float mid = __uint_as_float(((unsigned)bin << 20) | 0x00080000u);
        lwv[k] = (double)c * (double)mid;
        cs += c; wsd += lwv[k];
    }
    unsigned* pc = lhc;   // reuse LDS
    pc[t] = cs; ps[t] = wsd;
    __syncthreads();
    for (int off = 1; off < 256; off <<= 1) {
        const unsigned addc = (t >= off) ? pc[t - off] : 0u;
        const double   adds = (t >= off) ? ps[t - off] : 0.0;
        __syncthreads();
        pc[t] += addc; ps[t] += adds;
        __syncthreads();
    }
    const unsigned n = pc[255];                    // exact masked count
    const unsigned drop = n >> 2;
    const unsigned keep = n - drop;
    const double denom = (double)(keep > 0u ? keep : 1u);
    const unsigned long long sa_bits =
        __hip_atomic_load((const unsigned long long*)(ws + WS_SUM_ALL),
                          __ATOMIC_RELAXED, __HIP_MEMORY_SCOPE_AGENT);
    const double sum_all = __longlong_as_double((long long)sa_bits);

    if (drop == 0) {
        if (t == 0) out[0] = (float)(sum_all / denom);
        return;
    }

    const unsigned inclc = pc[t];
    const unsigned exclc = inclc - cs;
    if (inclc >= drop && exclc < drop) {
        unsigned cum = exclc;
        double scum = ps[t] - wsd;   // midpoint-weighted sum of bins before this chunk
        for (int k = 0; k < 16; ++k) {
            const unsigned c = lc[k];
            if (cum + c >= drop) {
                const unsigned bin1 = (unsigned)(t * 16 + k);
                const unsigned tgt1 = drop - cum;   // items taken inside bin1
                const float mid1 = __uint_as_float((bin1 << 20) | 0x00080000u);
                const double dropped = scum + (double)tgt1 * (double)mid1;
                out[0] = (float)((sum_all - dropped) / denom);
                break;
            }
            cum += c;
            scum += lwv[k];
        }
    }
}

extern "C" void kernel_launch(void* const* d_in, const int* in_sizes, int n_in,
                              void* d_out, int out_size, void* d_ws, size_t ws_size,
                              hipStream_t stream)
{
    const float* gt  = (const float*)d_in[0];
    const float* pd  = (const float*)d_in[1];
    const int*   p1x = (const int*)d_in[2];
    const int*   p1y = (const int*)d_in[3];
    const int*   p2x = (const int*)d_in[4];
    const int*   p2y = (const int*)d_in[5];
    const int*   p3x = (const int*)d_in[6];
    const int*   p3y = (const int*)d_in[7];
    unsigned char* ws = (unsigned char*)d_ws;
    float* out = (float*)d_out;

    k_pack   <<<dim3(GRIDP), dim3(256), 0, stream>>>(gt, pd, ws);
    k_compute<<<dim3(GRIDC), dim3(256), 0, stream>>>(p1x, p1y, p2x, p2y, p3x, p3y, ws, out);
}

// Round 10
// 139.467 us; speedup vs baseline: 1.0502x; 1.0502x over previous
//
#include <hip/hip_runtime.h>
#include <hip/hip_fp16.h>
#include <stdint.h>

// ---------------- problem constants ----------------
constexpr int Wd  = 640;
constexpr int Hd  = 480;
constexpr int Bd  = 8;
constexpr int Gd  = 368640;          // int(B*H*W*0.15)
constexpr int HWd = Hd * Wd;         // 307200
constexpr int GRIDP = HWd / 256;     // 1200
constexpr int GRIDC = Gd / 256;      // 1440  (1 thread/group: max gather ILP)
constexpr int NBIN  = 4096;          // top-12-bit count histogram
constexpr int NREP  = 4;             // global hist replicas (cut hot-bin contention)

// ---------------- workspace layout (bytes) ----------------
#define WS_SUM_ALL  0                        // double: exact sum of masked L
#define WS_DONE1    32                       // u32: completion counter
#define HISTC_OFF   64                       // NREP x NBIN u32 (count per bin)
#define CTRL_BYTES  (HISTC_OFF + NREP*NBIN*4)
#define CTRL_WORDS  (CTRL_BYTES / 4)
#define PACK_OFF    ((CTRL_BYTES + 255) & ~255)   // __half pk[HWd][16], 32B/pixel

// ---------------- kernel 0: repack depth to fp16 (pixel-major, batch-minor) + zero ctrl ----
// One pixel's 8 (gt,pd) pairs = 32B = one aligned segment -> 2 float4 gathers.
__global__ __launch_bounds__(256) void k_pack(const float* __restrict__ gt,
                                              const float* __restrict__ pd,
                                              unsigned char* __restrict__ ws)
{
    const int o = blockIdx.x * 256 + threadIdx.x;
    __half h[16];
#pragma unroll
    for (int b = 0; b < Bd; ++b) {
        h[2 * b]     = __float2half(gt[b * HWd + o]);
        h[2 * b + 1] = __float2half(pd[b * HWd + o]);
    }
    float4* __restrict__ dst = (float4*)(ws + PACK_OFF) + (size_t)o * 2;
    const float4* hv = (const float4*)h;
    dst[0] = hv[0];
    dst[1] = hv[1];

    if (blockIdx.x == 0) {
        unsigned* __restrict__ ctrl = (unsigned*)ws;
        for (int k = threadIdx.x; k < CTRL_WORDS; k += 256) ctrl[k] = 0u;
    }
}

// ---------------- kernel 1: single-pass L + mask + count-hist + fused select ----------------
// LESSONS BAKED IN:
//  - 1 thread/group, upfront independent float4 gathers, NO vgpr cap (R3/R7:
//    split layout -> VGPR 32 -> serialized gathers, +40us).
//  - NO __threadfence (R4: agent fence = per-XCD L2 writeback+invalidate, +65us).
//  - COUNT-ONLY hist + 4x replicas (R9: removed hot-bin atomic serialization).
//  - fp16 pack (R10): halves gather bytes 61->~35MB; depth ulp 4.9e-4 ->
//    output err ~2e-3 << 4.16e-2 threshold (harness rounds to bf16 anyway).
// n = exact hist total; sum_all = exact (1 double atomic per block); dropped
// mass = bin-midpoint approx, worst-case (dropped/denom)*2^-4 ~ 6e-3.
__global__ __launch_bounds__(256) void k_compute(
    const int* __restrict__ p1x, const int* __restrict__ p1y,
    const int* __restrict__ p2x, const int* __restrict__ p2y,
    const int* __restrict__ p3x, const int* __restrict__ p3y,
    unsigned char* __restrict__ ws, float* __restrict__ out)
{
    __shared__ unsigned lhc[NBIN];
    __shared__ double   ps[256];
    __shared__ double   wsum[4];
    __shared__ int      lastflag;
    const int t = threadIdx.x;
    for (int k = t; k < NBIN; k += 256) lhc[k] = 0u;
    __syncthreads();

    const int g = blockIdx.x * 256 + t;
    const int x1 = p1x[g], y1 = p1y[g];
    const int x2 = p2x[g], y2 = p2y[g];
    const int x3 = p3x[g], y3 = p3y[g];
    const int o1 = y1 * Wd + x1, o2 = y2 * Wd + x2, o3 = y3 * Wd + x3;
    const float u1 = (float)x1 - 320.0f, v1 = (float)y1 - 240.0f;
    const float u2 = (float)x2 - 320.0f, v2 = (float)y2 - 240.0f;
    const float u3 = (float)x3 - 320.0f, v3 = (float)y3 - 240.0f;
    constexpr float RF = 1.0f / 519.0f;

    // 3 random 32B segments, 6 independent float4 loads; first 3 cover batches 0-3
    const float4* __restrict__ pk2 = (const float4*)(ws + PACK_OFF);
    float4 A[2], Bv[2], Cv[2];
    A[0]  = pk2[(size_t)o1 * 2];
    Bv[0] = pk2[(size_t)o2 * 2];
    Cv[0] = pk2[(size_t)o3 * 2];
    A[1]  = pk2[(size_t)o1 * 2 + 1];
    Bv[1] = pk2[(size_t)o2 * 2 + 1];
    Cv[1] = pk2[(size_t)o3 * 2 + 1];
    const __half* __restrict__ P1 = (const __half*)A;
    const __half* __restrict__ P2 = (const __half*)Bv;
    const __half* __restrict__ P3 = (const __half*)Cv;

    double lsum = 0.0;

#pragma unroll
    for (int b = 0; b < Bd; ++b) {
        const float d1 = __half2float(P1[2 * b]), e1 = __half2float(P1[2 * b + 1]);
        const float d2 = __half2float(P2[2 * b]), e2 = __half2float(P2[2 * b + 1]);
        const float d3 = __half2float(P3[2 * b]), e3 = __half2float(P3[2 * b + 1]);

        const float a1 = fabsf(d1) * RF, a2 = fabsf(d2) * RF, a3 = fabsf(d3) * RF;
        const float gx1 = u1 * a1, gy1 = v1 * a1;
        const float gx2 = u2 * a2, gy2 = v2 * a2;
        const float gx3 = u3 * a3, gy3 = v3 * a3;

        const float D0x = gx2 - gx1, D0y = gy2 - gy1, D0z = d2 - d1;
        const float D1x = gx3 - gx1, D1y = gy3 - gy1, D1z = d3 - d1;
        const float D2x = gx3 - gx2, D2y = gy3 - gy2, D2z = d3 - d2;

        const float e00 = D0x*D0x + D0y*D0y + D0z*D0z;
        const float e11 = D1x*D1x + D1y*D1y + D1z*D1z;
        const float e22 = D2x*D2x + D2y*D2y + D2z*D2z;
        const float e01 = D0x*D1x + D0y*D1y + D0z*D1z;
        const float e02 = D0x*D2x + D0y*D2y + D0z*D2z;
        const float e12 = D1x*D2x + D1y*D2y + D1z*D2z;
        constexpr float DC = 0.867f;
        // diagonal: |e00| > DC*(e00+1e-8)  <=>  e00 > 1e-8*DC/(1-DC) = 6.519e-8
        constexpr float DIAG = 6.519e-8f;
        const float n01 = sqrtf(e00 * e11);
        const float n02 = sqrtf(e00 * e22);
        const float n12 = sqrtf(e11 * e22);
        int cnt = 0;
        cnt += (e00 > DIAG);
        cnt += (e11 > DIAG);
        cnt += (e22 > DIAG);
        cnt += 2 * (fabsf(e01) > DC * (n01 + 1e-8f));
        cnt += 2 * (fabsf(e02) > DC * (n02 + 1e-8f));
        cnt += 2 * (fabsf(e12) > DC * (n12 + 1e-8f));
        const bool mask_cos = cnt > 3;

        const bool mx = (fabsf(D0x) < 0.01f) | (fabsf(D1x) < 0.01f) | (fabsf(D2x) < 0.01f);
        const bool my = (fabsf(D0y) < 0.01f) | (fabsf(D1y) < 0.01f) | (fabsf(D2y) < 0.01f);
        const bool mz = (fabsf(D0z) < 0.01f) | (fabsf(D1z) < 0.01f) | (fabsf(D2z) < 0.01f);
        const bool mask = !((mx && my && mz) || mask_cos);

        const float b1s = fabsf(e1) * RF, b2s = fabsf(e2) * RF, b3s = fabsf(e3) * RF;
        float qx1 = u1 * b1s, qy1 = v1 * b1s, qz1 = e1;
        float qx2 = u2 * b2s, qy2 = v2 * b2s, qz2 = e2;
        float qx3 = u3 * b3s, qy3 = v3 * b3s, qz3 = e3;
        // reference's zmask broadcast: coordinate ROW c of all points
        const bool zm0 = (qz1 == 0.0f), zm1 = (qz2 == 0.0f), zm2 = (qz3 == 0.0f);
        if (zm0) { qx1 = qx2 = qx3 = 1e-4f; }
        if (zm1) { qy1 = qy2 = qy3 = 1e-4f; }
        if (zm2) { qz1 = qz2 = qz3 = 1e-4f; }

        const float P0x = qx2 - qx1, P0y = qy2 - qy1, P0z = qz2 - qz1;
        const float Q1x = qx3 - qx1, Q1y = qy3 - qy1, Q1z = qz3 - qz1;

        const float gnx = D0y * D1z - D0z * D1y;
        const float gny = D0z * D1x - D0x * D1z;
        const float gnz = D0x * D1y - D0y * D1x;
        const float dnx = P0y * Q1z - P0z * Q1y;
        const float dny = P0z * Q1x - P0x * Q1z;
        const float dnz = P0x * Q1y - P0y * Q1x;

        float gnn = sqrtf(gnx*gnx + gny*gny + gnz*gnz);
        float dnn = sqrtf(dnx*dnx + dny*dny + dnz*dnz);
        if (gnn == 0.0f) gnn = 0.01f;
        if (dnn == 0.0f) dnn = 0.01f;
        const float rg = 1.0f / gnn, rd = 1.0f / dnn;
        const float L = fabsf(gnx*rg - dnx*rd) + fabsf(gny*rg - dny*rd) + fabsf(gnz*rg - dnz*rd);

        if (mask) {
            lsum += (double)L;
            atomicAdd(&lhc[__float_as_uint(L) >> 20], 1u);
        }
    }

    // exact sum_all: wave shuffle then one double atomic per block
#pragma unroll
    for (int off = 32; off > 0; off >>= 1) lsum += __shfl_down(lsum, off);
    if ((t & 63) == 0) wsum[t >> 6] = lsum;
    __syncthreads();
    if (t == 0)
        atomicAdd((double*)(ws + WS_SUM_ALL), wsum[0] + wsum[1] + wsum[2] + wsum[3]);

    // merge count hist into this block's replica
    unsigned* __restrict__ gc = (unsigned*)(ws + HISTC_OFF) + (blockIdx.x & (NREP - 1)) * NBIN;
    for (int k = t; k < NBIN; k += 256) {
        const unsigned c = lhc[k];
        if (c) atomicAdd(&gc[k], c);
    }

    // ---- fence-free completion: __syncthreads() drains vmcnt for every wave ----
    __syncthreads();
    if (t == 0) {
        const unsigned prev = __hip_atomic_fetch_add((unsigned*)(ws + WS_DONE1), 1u,
                                                     __ATOMIC_RELAXED, __HIP_MEMORY_SCOPE_AGENT);
        lastflag = (prev == (unsigned)(gridDim.x - 1));
    }
    __syncthreads();
    if (!lastflag) return;

    // ---- last block: scan counts -> n, cutoff bin; midpoint-approx dropped sum ----
    const unsigned* __restrict__ gcb = (const unsigned*)(ws + HISTC_OFF);
    unsigned lc[16]; double lwv[16];
    unsigned cs = 0; double wsd = 0.0;
#pragma unroll
    for (int k = 0; k < 16; ++k) {
        const int bin = t * 16 + k;
        unsigned c = 0;
#pragma unroll
        for (int r = 0; r < NREP; ++r)
            c += __hip_atomic_load(&gcb[r * NBIN + bin],
                                   __ATOMIC_RELAXED, __HIP_MEMORY_SCOPE_AGENT);
        lc[k] = c;
        const float mid = __uint_as_float(((unsigned)bin << 20) | 0x00080000u);
        lwv[k] = (double)c * (double)mid;
        cs += c; wsd += lwv[k];
    }
    unsigned* pc = lhc;   // reuse LDS
    pc[t] = cs; ps[t] = wsd;
    __syncthreads();
    for (int off = 1; off < 256; off <<= 1) {
        const unsigned addc = (t >= off) ? pc[t - off] : 0u;
        const double   adds = (t >= off) ? ps[t - off] : 0.0;
        __syncthreads();
        pc[t] += addc; ps[t] += adds;
        __syncthreads();
    }
    const unsigned n = pc[255];                    // exact masked count
    const unsigned drop = n >> 2;
    const unsigned keep = n - drop;
    const double denom = (double)(keep > 0u ? keep : 1u);
    const unsigned long long sa_bits =
        __hip_atomic_load((const unsigned long long*)(ws + WS_SUM_ALL),
                          __ATOMIC_RELAXED, __HIP_MEMORY_SCOPE_AGENT);
    const double sum_all = __longlong_as_double((long long)sa_bits);

    if (drop == 0) {
        if (t == 0) out[0] = (float)(sum_all / denom);
        return;
    }

    const unsigned inclc = pc[t];
    const unsigned exclc = inclc - cs;
    if (inclc >= drop && exclc < drop) {
        unsigned cum = exclc;
        double scum = ps[t] - wsd;   // midpoint-weighted sum of bins before this chunk
        for (int k = 0; k < 16; ++k) {
            const unsigned c = lc[k];
            if (cum + c >= drop) {
                const unsigned bin1 = (unsigned)(t * 16 + k);
                const unsigned tgt1 = drop - cum;   // items taken inside bin1
                const float mid1 = __uint_as_float((bin1 << 20) | 0x00080000u);
                const double dropped = scum + (double)tgt1 * (double)mid1;
                out[0] = (float)((sum_all - dropped) / denom);
                break;
            }
            cum += c;
            scum += lwv[k];
        }
    }
}

extern "C" void kernel_launch(void* const* d_in, const int* in_sizes, int n_in,
                              void* d_out, int out_size, void* d_ws, size_t ws_size,
                              hipStream_t stream)
{
    const float* gt  = (const float*)d_in[0];
    const float* pd  = (const float*)d_in[1];
    const int*   p1x = (const int*)d_in[2];
    const int*   p1y = (const int*)d_in[3];
    const int*   p2x = (const int*)d_in[4];
    const int*   p2y = (const int*)d_in[5];
    const int*   p3x = (const int*)d_in[6];
    const int*   p3y = (const int*)d_in[7];
    unsigned char* ws = (unsigned char*)d_ws;
    float* out = (float*)d_out;

    k_pack   <<<dim3(GRIDP), dim3(256), 0, stream>>>(gt, pd, ws);
    k_compute<<<dim3(GRIDC), dim3(256), 0, stream>>>(p1x, p1y, p2x, p2y, p3x, p3y, ws, out);
}

// Round 11
// 123.327 us; speedup vs baseline: 1.1877x; 1.1309x over previous
//
#include <hip/hip_runtime.h>
#include <hip/hip_fp16.h>
#include <stdint.h>

// ---------------- problem constants ----------------
constexpr int Wd  = 640;
constexpr int Hd  = 480;
constexpr int Bd  = 8;
constexpr int Gd  = 368640;          // int(B*H*W*0.15)
constexpr int HWd = Hd * Wd;         // 307200
constexpr int GRIDP = HWd / 256;     // 1200
constexpr int GRIDC = Gd / 512;      // 720  (2 groups per thread)
constexpr int NBIN  = 4096;          // top-12-bit count histogram
constexpr int NREP  = 4;             // global hist replicas (cut hot-bin contention)

// ---------------- workspace layout (bytes) ----------------
#define WS_SUM_ALL  0                        // double: exact sum of masked L
#define WS_DONE1    32                       // u32: completion counter
#define HISTC_OFF   64                       // NREP x NBIN u32 (count per bin)
#define CTRL_BYTES  (HISTC_OFF + NREP*NBIN*4)
#define CTRL_WORDS  (CTRL_BYTES / 4)
#define PACK_OFF    ((CTRL_BYTES + 255) & ~255)   // __half pk[HWd][16], 32B/pixel

// ---------------- kernel 0: repack depth to fp16 (pixel-major, batch-minor) + zero ctrl ----
__global__ __launch_bounds__(256) void k_pack(const float* __restrict__ gt,
                                              const float* __restrict__ pd,
                                              unsigned char* __restrict__ ws)
{
    const int o = blockIdx.x * 256 + threadIdx.x;
    __half h[16];
#pragma unroll
    for (int b = 0; b < Bd; ++b) {
        h[2 * b]     = __float2half(gt[b * HWd + o]);
        h[2 * b + 1] = __float2half(pd[b * HWd + o]);
    }
    float4* __restrict__ dst = (float4*)(ws + PACK_OFF) + (size_t)o * 2;
    const float4* hv = (const float4*)h;
    dst[0] = hv[0];
    dst[1] = hv[1];

    if (blockIdx.x == 0) {
        unsigned* __restrict__ ctrl = (unsigned*)ws;
        for (int k = threadIdx.x; k < CTRL_WORDS; k += 256) ctrl[k] = 0u;
    }
}

// per-group body: 8 batches from fp16-packed point data
__device__ __forceinline__ void process_group(
    const __half* __restrict__ P1, const __half* __restrict__ P2,
    const __half* __restrict__ P3,
    float u1, float v1, float u2, float v2, float u3, float v3,
    double& lsum, unsigned* __restrict__ lhc)
{
    constexpr float RF = 1.0f / 519.0f;
#pragma unroll
    for (int b = 0; b < Bd; ++b) {
        const float d1 = __half2float(P1[2 * b]), e1 = __half2float(P1[2 * b + 1]);
        const float d2 = __half2float(P2[2 * b]), e2 = __half2float(P2[2 * b + 1]);
        const float d3 = __half2float(P3[2 * b]), e3 = __half2float(P3[2 * b + 1]);

        const float a1 = fabsf(d1) * RF, a2 = fabsf(d2) * RF, a3 = fabsf(d3) * RF;
        const float gx1 = u1 * a1, gy1 = v1 * a1;
        const float gx2 = u2 * a2, gy2 = v2 * a2;
        const float gx3 = u3 * a3, gy3 = v3 * a3;

        const float D0x = gx2 - gx1, D0y = gy2 - gy1, D0z = d2 - d1;
        const float D1x = gx3 - gx1, D1y = gy3 - gy1, D1z = d3 - d1;
        const float D2x = gx3 - gx2, D2y = gy3 - gy2, D2z = d3 - d2;

        const float e00 = D0x*D0x + D0y*D0y + D0z*D0z;
        const float e11 = D1x*D1x + D1y*D1y + D1z*D1z;
        const float e22 = D2x*D2x + D2y*D2y + D2z*D2z;
        const float e01 = D0x*D1x + D0y*D1y + D0z*D1z;
        const float e02 = D0x*D2x + D0y*D2y + D0z*D2z;
        const float e12 = D1x*D2x + D1y*D2y + D1z*D2z;
        constexpr float DC = 0.867f;
        // diagonal: |e00| > DC*(e00+1e-8)  <=>  e00 > 1e-8*DC/(1-DC)
        constexpr float DIAG = 6.519e-8f;
        const float n01 = sqrtf(e00 * e11);
        const float n02 = sqrtf(e00 * e22);
        const float n12 = sqrtf(e11 * e22);
        int cnt = 0;
        cnt += (e00 > DIAG);
        cnt += (e11 > DIAG);
        cnt += (e22 > DIAG);
        cnt += 2 * (fabsf(e01) > DC * (n01 + 1e-8f));
        cnt += 2 * (fabsf(e02) > DC * (n02 + 1e-8f));
        cnt += 2 * (fabsf(e12) > DC * (n12 + 1e-8f));
        const bool mask_cos = cnt > 3;

        const bool mx = (fabsf(D0x) < 0.01f) | (fabsf(D1x) < 0.01f) | (fabsf(D2x) < 0.01f);
        const bool my = (fabsf(D0y) < 0.01f) | (fabsf(D1y) < 0.01f) | (fabsf(D2y) < 0.01f);
        const bool mz = (fabsf(D0z) < 0.01f) | (fabsf(D1z) < 0.01f) | (fabsf(D2z) < 0.01f);
        const bool mask = !((mx && my && mz) || mask_cos);

        const float b1s = fabsf(e1) * RF, b2s = fabsf(e2) * RF, b3s = fabsf(e3) * RF;
        float qx1 = u1 * b1s, qy1 = v1 * b1s, qz1 = e1;
        float qx2 = u2 * b2s, qy2 = v2 * b2s, qz2 = e2;
        float qx3 = u3 * b3s, qy3 = v3 * b3s, qz3 = e3;
        // reference's zmask broadcast: coordinate ROW c of all points
        const bool zm0 = (qz1 == 0.0f), zm1 = (qz2 == 0.0f), zm2 = (qz3 == 0.0f);
        if (zm0) { qx1 = qx2 = qx3 = 1e-4f; }
        if (zm1) { qy1 = qy2 = qy3 = 1e-4f; }
        if (zm2) { qz1 = qz2 = qz3 = 1e-4f; }

        const float P0x = qx2 - qx1, P0y = qy2 - qy1, P0z = qz2 - qz1;
        const float Q1x = qx3 - qx1, Q1y = qy3 - qy1, Q1z = qz3 - qz1;

        const float gnx = D0y * D1z - D0z * D1y;
        const float gny = D0z * D1x - D0x * D1z;
        const float gnz = D0x * D1y - D0y * D1x;
        const float dnx = P0y * Q1z - P0z * Q1y;
        const float dny = P0z * Q1x - P0x * Q1z;
        const float dnz = P0x * Q1y - P0y * Q1x;

        float gnn = sqrtf(gnx*gnx + gny*gny + gnz*gnz);
        float dnn = sqrtf(dnx*dnx + dny*dny + dnz*dnz);
        if (gnn == 0.0f) gnn = 0.01f;
        if (dnn == 0.0f) dnn = 0.01f;
        const float rg = 1.0f / gnn, rd = 1.0f / dnn;
        const float L = fabsf(gnx*rg - dnx*rd) + fabsf(gny*rg - dny*rd) + fabsf(gnz*rg - dnz*rd);

        if (mask) {
            lsum += (double)L;
            atomicAdd(&lhc[__float_as_uint(L) >> 20], 1u);
        }
    }
}

// ---------------- kernel 1: 2 groups/thread, single pass, fused select ----------------
// LESSONS BAKED IN:
//  - NO __threadfence (R4: agent fence = per-XCD L2 wb+inv, +65us).
//  - COUNT-ONLY hist + 4x replicas (R9: killed hot-bin atomic serialization).
//  - fp16 pack (R10): FETCH 61->49MB; gathers proved LATENCY-bound.
//  - R11: 2 groups/thread, 12 upfront independent float4 gathers. Group-B's
//    loads stay in flight (vmcnt(6)) while group-A computes — attacks the
//    95k-cycle stall share. Watch VGPR_Count: >=80 good, <=48 = compiler
//    serialized (R3/R7 failure mode) -> revert.
__global__ __launch_bounds__(256) void k_compute(
    const int* __restrict__ p1x, const int* __restrict__ p1y,
    const int* __restrict__ p2x, const int* __restrict__ p2y,
    const int* __restrict__ p3x, const int* __restrict__ p3y,
    unsigned char* __restrict__ ws, float* __restrict__ out)
{
    __shared__ unsigned lhc[NBIN];
    __shared__ double   ps[256];
    __shared__ double   wsum[4];
    __shared__ int      lastflag;
    const int t = threadIdx.x;
    for (int k = t; k < NBIN; k += 256) lhc[k] = 0u;
    __syncthreads();

    const int g0 = blockIdx.x * 256 + t;
    const int g1 = g0 + Gd / 2;

    // indices for both groups
    const int xa1 = p1x[g0], ya1 = p1y[g0], xa2 = p2x[g0], ya2 = p2y[g0], xa3 = p3x[g0], ya3 = p3y[g0];
    const int xb1 = p1x[g1], yb1 = p1y[g1], xb2 = p2x[g1], yb2 = p2y[g1], xb3 = p3x[g1], yb3 = p3y[g1];
    const int oa1 = ya1 * Wd + xa1, oa2 = ya2 * Wd + xa2, oa3 = ya3 * Wd + xa3;
    const int ob1 = yb1 * Wd + xb1, ob2 = yb2 * Wd + xb2, ob3 = yb3 * Wd + xb3;

    const float4* __restrict__ pk2 = (const float4*)(ws + PACK_OFF);
    // 12 independent gathers: group A's 6 first (compute A gates on vmcnt(6))
    float4 A0[2], A1[2], A2[2], B0[2], B1[2], B2[2];
    A0[0] = pk2[(size_t)oa1 * 2];     A1[0] = pk2[(size_t)oa2 * 2];     A2[0] = pk2[(size_t)oa3 * 2];
    A0[1] = pk2[(size_t)oa1 * 2 + 1]; A1[1] = pk2[(size_t)oa2 * 2 + 1]; A2[1] = pk2[(size_t)oa3 * 2 + 1];
    B0[0] = pk2[(size_t)ob1 * 2];     B1[0] = pk2[(size_t)ob2 * 2];     B2[0] = pk2[(size_t)ob3 * 2];
    B0[1] = pk2[(size_t)ob1 * 2 + 1]; B1[1] = pk2[(size_t)ob2 * 2 + 1]; B2[1] = pk2[(size_t)ob3 * 2 + 1];

    double lsum = 0.0;

    process_group((const __half*)A0, (const __half*)A1, (const __half*)A2,
                  (float)xa1 - 320.0f, (float)ya1 - 240.0f,
                  (float)xa2 - 320.0f, (float)ya2 - 240.0f,
                  (float)xa3 - 320.0f, (float)ya3 - 240.0f, lsum, lhc);
    process_group((const __half*)B0, (const __half*)B1, (const __half*)B2,
                  (float)xb1 - 320.0f, (float)yb1 - 240.0f,
                  (float)xb2 - 320.0f, (float)yb2 - 240.0f,
                  (float)xb3 - 320.0f, (float)yb3 - 240.0f, lsum, lhc);

    // exact sum_all: wave shuffle then one double atomic per block
#pragma unroll
    for (int off = 32; off > 0; off >>= 1) lsum += __shfl_down(lsum, off);
    if ((t & 63) == 0) wsum[t >> 6] = lsum;
    __syncthreads();
    if (t == 0)
        atomicAdd((double*)(ws + WS_SUM_ALL), wsum[0] + wsum[1] + wsum[2] + wsum[3]);

    // merge count hist into this block's replica
    unsigned* __restrict__ gc = (unsigned*)(ws + HISTC_OFF) + (blockIdx.x & (NREP - 1)) * NBIN;
    for (int k = t; k < NBIN; k += 256) {
        const unsigned c = lhc[k];
        if (c) atomicAdd(&gc[k], c);
    }

    // ---- fence-free completion: __syncthreads() drains vmcnt for every wave ----
    __syncthreads();
    if (t == 0) {
        const unsigned prev = __hip_atomic_fetch_add((unsigned*)(ws + WS_DONE1), 1u,
                                                     __ATOMIC_RELAXED, __HIP_MEMORY_SCOPE_AGENT);
        lastflag = (prev == (unsigned)(gridDim.x - 1));
    }
    __syncthreads();
    if (!lastflag) return;

    // ---- last block: scan counts -> n, cutoff bin; midpoint-approx dropped sum ----
    const unsigned* __restrict__ gcb = (const unsigned*)(ws + HISTC_OFF);
    unsigned lc[16]; double lwv[16];
    unsigned cs = 0; double wsd = 0.0;
#pragma unroll
    for (int k = 0; k < 16; ++k) {
        const int bin = t * 16 + k;
        unsigned c = 0;
#pragma unroll
        for (int r = 0; r < NREP; ++r)
            c += __hip_atomic_load(&gcb[r * NBIN + bin],
                                   __ATOMIC_RELAXED, __HIP_MEMORY_SCOPE_AGENT);
        lc[k] = c;
        const float mid = __uint_as_float(((unsigned)bin << 20) | 0x00080000u);
        lwv[k] = (double)c * (double)mid;
        cs += c; wsd += lwv[k];
    }
    unsigned* pc = lhc;   // reuse LDS
    pc[t] = cs; ps[t] = wsd;
    __syncthreads();
    for (int off = 1; off < 256; off <<= 1) {
        const unsigned addc = (t >= off) ? pc[t - off] : 0u;
        const double   adds = (t >= off) ? ps[t - off] : 0.0;
        __syncthreads();
        pc[t] += addc; ps[t] += adds;
        __syncthreads();
    }
    const unsigned n = pc[255];                    // exact masked count
    const unsigned drop = n >> 2;
    const unsigned keep = n - drop;
    const double denom = (double)(keep > 0u ? keep : 1u);
    const unsigned long long sa_bits =
        __hip_atomic_load((const unsigned long long*)(ws + WS_SUM_ALL),
                          __ATOMIC_RELAXED, __HIP_MEMORY_SCOPE_AGENT);
    const double sum_all = __longlong_as_double((long long)sa_bits);

    if (drop == 0) {
        if (t == 0) out[0] = (float)(sum_all / denom);
        return;
    }

    const unsigned inclc = pc[t];
    const unsigned exclc = inclc - cs;
    if (inclc >= drop && exclc < drop) {
        unsigned cum = exclc;
        double scum = ps[t] - wsd;   // midpoint-weighted sum of bins before this chunk
        for (int k = 0; k < 16; ++k) {
            const unsigned c = lc[k];
            if (cum + c >= drop) {
                const unsigned bin1 = (unsigned)(t * 16 + k);
                const unsigned tgt1 = drop - cum;   // items taken inside bin1
                const float mid1 = __uint_as_float((bin1 << 20) | 0x00080000u);
                const double dropped = scum + (double)tgt1 * (double)mid1;
                out[0] = (float)((sum_all - dropped) / denom);
                break;
            }
            cum += c;
            scum += lwv[k];
        }
    }
}

extern "C" void kernel_launch(void* const* d_in, const int* in_sizes, int n_in,
                              void* d_out, int out_size, void* d_ws, size_t ws_size,
                              hipStream_t stream)
{
    const float* gt  = (const float*)d_in[0];
    const float* pd  = (const float*)d_in[1];
    const int*   p1x = (const int*)d_in[2];
    const int*   p1y = (const int*)d_in[3];
    const int*   p2x = (const int*)d_in[4];
    const int*   p2y = (const int*)d_in[5];
    const int*   p3x = (const int*)d_in[6];
    const int*   p3y = (const int*)d_in[7];
    unsigned char* ws = (unsigned char*)d_ws;
    float* out = (float*)d_out;

    k_pack   <<<dim3(GRIDP), dim3(256), 0, stream>>>(gt, pd, ws);
    k_compute<<<dim3(GRIDC), dim3(256), 0, stream>>>(p1x, p1y, p2x, p2y, p3x, p3y, ws, out);
}